// Round 11
// baseline (697.227 us; speedup 1.0000x reference)
//
#include <hip/hip_runtime.h>

#define N_RAYS 16384
#define NSAMP  96
#define GD 128
#define GH 128
#define GW 128
#define C_IN  32
#define C_HID 32
#define C_OUT 16
#define M_PTS (N_RAYS * NSAMP)       // 1,572,864 (divisible by 256)
#define TPA 16                        // tiles per axis (128/8)
#define NTILES (TPA*TPA*TPA)          // 4096
#define TW 8                          // tile width (voxels)
#define TVOX (TW*TW*TW)               // 512 voxels per tile
#define CHUNK 256                     // entries staged per K4 inner pass

__device__ __forceinline__ int clampi(int v, int hi) { return min(max(v, 0), hi); }

struct TileSpan { int txa, txb, tya, tyb, tza, tzb; };
__device__ __forceinline__ TileSpan tile_span(int X, int Y, int Z) {
    TileSpan s;
    s.txa = clampi(X,   GW-1) >> 3;  s.txb = clampi(X+1, GW-1) >> 3;
    s.tya = clampi(Y,   GH-1) >> 3;  s.tyb = clampi(Y+1, GH-1) >> 3;
    s.tza = clampi(Z,   GD-1) >> 3;  s.tzb = clampi(Z+1, GD-1) >> 3;
    return s;
}

// ============================================================================
// K1 (LITE): positions + key + per-tile histogram ONLY. The gather+MLP moved
// into K4 where entries are tile-grouped (L2-local gather). No po array.
// ============================================================================
__global__ __launch_bounds__(256) void k1_pos(
    const float* __restrict__ origins, const float* __restrict__ dirs,
    const float* __restrict__ nearv,   const float* __restrict__ farv,
    float4* __restrict__ pf, unsigned* __restrict__ counts)
{
    __shared__ unsigned lcnt[NTILES];
    for (int i = threadIdx.x; i < NTILES; i += 256) lcnt[i] = 0;
    __syncthreads();

    int pid = blockIdx.x * 256 + threadIdx.x;     // always < M_PTS (exact grid)
    int ray = pid / NSAMP;
    int s   = pid - ray * NSAMP;

    float nr = nearv[ray], fr = farv[ray];
    float t  = nr + (fr - nr) * ((float)s * (1.0f / (NSAMP - 1)));
    float px = fmaf(t, dirs[ray*3+0], origins[ray*3+0]);
    float py = fmaf(t, dirs[ray*3+1], origins[ray*3+1]);
    float pz = fmaf(t, dirs[ray*3+2], origins[ray*3+2]);

    float cx = ((px + 1.0f) * (float)GW - 1.0f) * 0.5f;
    float cy = ((py + 1.0f) * (float)GH - 1.0f) * 0.5f;
    float cz = ((pz + 1.0f) * (float)GD - 1.0f) * 0.5f;
    float fxf = floorf(cx), fyf = floorf(cy), fzf = floorf(cz);
    float fx = cx - fxf, fy = cy - fyf, fz = cz - fzf;
    int X = (int)fxf, Y = (int)fyf, Z = (int)fzf;

    unsigned key = ((unsigned)(X + 256) & 511u)
                 | (((unsigned)(Y + 256) & 511u) << 9)
                 | (((unsigned)(Z + 256) & 511u) << 18);
    pf[pid] = make_float4(fx, fy, fz, __uint_as_float(key));

    TileSpan ts = tile_span(X, Y, Z);
    #pragma unroll
    for (int ez = 0; ez < 2; ++ez) {
        if (ez && ts.tzb == ts.tza) continue;
        #pragma unroll
        for (int ey = 0; ey < 2; ++ey) {
            if (ey && ts.tyb == ts.tya) continue;
            #pragma unroll
            for (int ex = 0; ex < 2; ++ex) {
                if (ex && ts.txb == ts.txa) continue;
                int tt = ((ts.tza + ez) * TPA + (ts.tya + ey)) * TPA + (ts.txa + ex);
                atomicAdd(&lcnt[tt], 1u);
            }
        }
    }
    __syncthreads();
    for (int i = threadIdx.x; i < NTILES; i += 256)
        if (lcnt[i]) atomicAdd(&counts[i], lcnt[i]);
}

// ============================================================================
// K2: exclusive scan of 4096 tile counts + heavy-first tile schedule.
// ============================================================================
__global__ __launch_bounds__(256) void k2_scan(
    const unsigned* __restrict__ counts,
    unsigned* __restrict__ offsets, unsigned* __restrict__ alloc,
    unsigned* __restrict__ order)
{
    __shared__ unsigned psum[256];
    __shared__ unsigned bh[256];
    __shared__ unsigned bb[256];
    int tid = threadIdx.x;
    unsigned base = tid * 16;
    unsigned ssum = 0;
    for (int i = 0; i < 16; ++i) ssum += counts[base + i];
    psum[tid] = ssum;
    bh[tid] = 0;
    __syncthreads();
    if (tid == 0) {
        unsigned r = 0;
        for (int i = 0; i < 256; ++i) { unsigned v = psum[i]; psum[i] = r; r += v; }
    }
    __syncthreads();
    unsigned run = psum[tid];
    for (int i = 0; i < 16; ++i) {
        unsigned v = counts[base + i];
        offsets[base + i] = run;
        alloc[base + i]   = run;
        run += v;
        atomicAdd(&bh[min(v >> 4, 255u)], 1u);
    }
    __syncthreads();
    if (tid == 0) {
        unsigned r = 0;
        for (int b = 255; b >= 0; --b) { unsigned v = bh[b]; bb[b] = r; r += v; }
    }
    __syncthreads();
    for (int i = 0; i < 16; ++i) {
        unsigned v = counts[base + i];
        unsigned slot = atomicAdd(&bb[min(v >> 4, 255u)], 1u);
        order[slot] = base + i;
    }
}

// ============================================================================
// K3: scatter point indices into per-tile segments (unchanged).
// ============================================================================
__global__ __launch_bounds__(256) void k3_scatter(
    const float4* __restrict__ pf, unsigned* __restrict__ alloc,
    unsigned* __restrict__ entries)
{
    __shared__ unsigned lcnt[NTILES];
    __shared__ unsigned lbase[NTILES];
    for (int i = threadIdx.x; i < NTILES; i += 256) lcnt[i] = 0;
    __syncthreads();

    int pid = blockIdx.x * 256 + threadIdx.x;
    float4 f = pf[pid];
    unsigned key = __float_as_uint(f.w);
    int X = (int)(key & 511u) - 256;
    int Y = (int)((key >> 9) & 511u) - 256;
    int Z = (int)((key >> 18) & 511u) - 256;
    TileSpan ts = tile_span(X, Y, Z);

    unsigned rnk[2][2][2];
    #pragma unroll
    for (int ez = 0; ez < 2; ++ez) {
        bool okz = (ez == 0) || (ts.tzb > ts.tza);
        #pragma unroll
        for (int ey = 0; ey < 2; ++ey) {
            bool oky = (ey == 0) || (ts.tyb > ts.tya);
            #pragma unroll
            for (int ex = 0; ex < 2; ++ex) {
                bool okx = (ex == 0) || (ts.txb > ts.txa);
                if (okz && oky && okx) {
                    int tt = ((ts.tza + ez) * TPA + (ts.tya + ey)) * TPA + (ts.txa + ex);
                    rnk[ez][ey][ex] = atomicAdd(&lcnt[tt], 1u);
                }
            }
        }
    }
    __syncthreads();
    for (int i = threadIdx.x; i < NTILES; i += 256)
        if (lcnt[i]) lbase[i] = atomicAdd(&alloc[i], lcnt[i]);
    __syncthreads();
    #pragma unroll
    for (int ez = 0; ez < 2; ++ez) {
        bool okz = (ez == 0) || (ts.tzb > ts.tza);
        #pragma unroll
        for (int ey = 0; ey < 2; ++ey) {
            bool oky = (ey == 0) || (ts.tyb > ts.tya);
            #pragma unroll
            for (int ex = 0; ex < 2; ++ex) {
                bool okx = (ex == 0) || (ts.txb > ts.txa);
                if (okz && oky && okx) {
                    int tt = ((ts.tza + ez) * TPA + (ts.tya + ey)) * TPA + (ts.txa + ex);
                    entries[lbase[tt] + rnk[ez][ey][ex]] = (unsigned)pid;
                }
            }
        }
    }
}

// ============================================================================
// K4 (FUSED): staging phase now does the trilinear GATHER + MLP per entry
// (tile-grouped entries -> the 8-corner gather hits a ~128 KB window, L2-hot),
// writing o[16] to LDS. Splat phase identical to r10 (register accumulators,
// int4 z-scan, wave-uniform per-layer guards, heavy-first order). The po
// global round-trip (100 MB write + ~115 MB read) is gone.
// ============================================================================
__global__ __launch_bounds__(256) void k4_fused(
    const float4* __restrict__ pf, const unsigned* __restrict__ entries,
    const unsigned* __restrict__ offsets, const unsigned* __restrict__ alloc,
    const unsigned* __restrict__ order,
    const float* __restrict__ enc, const int* __restrict__ gidx,
    const float* __restrict__ grid, const float* __restrict__ W0,
    const float* __restrict__ b0,   const float* __restrict__ W1,
    const float* __restrict__ b1,   float* __restrict__ out)
{
    __shared__ __attribute__((aligned(16))) float4 sA[CHUNK];   // fx,fy,fz, cx0|cx1|cy0|cy1
    __shared__ __attribute__((aligned(16))) int    sZ[CHUNK];   // st0|st1<<8 (255=out)
    __shared__ __attribute__((aligned(16))) float4 sO[4*CHUNK]; // o[16] planar [q][entry]

    int t  = order[blockIdx.x];      // heavy tiles scheduled first
    int tx = t & (TPA-1), ty = (t >> 4) & (TPA-1), tz = t >> 8;
    int ox = tx * TW, oy = ty * TW, oz = tz * TW;

    int tid  = threadIdx.x;
    int lane = tid & 63;
    int w    = tid >> 6;             // wave id, owns z-layers {2w, 2w+1}
    int vxa  = ox + (lane & 7);
    int vya  = oy + (lane >> 3);
    int l0   = 2*w, l1 = 2*w + 1;

    float accA[C_OUT], accB[C_OUT];
    #pragma unroll
    for (int c = 0; c < C_OUT; ++c) { accA[c] = 0.0f; accB[c] = 0.0f; }

    unsigned e0 = offsets[t], e1 = alloc[t];
    for (unsigned base = e0; base < e1; base += CHUNK) {
        int n = min((unsigned)CHUNK, e1 - base);
        if (tid < n) {
            unsigned p = entries[base + tid];
            float4 f = pf[p];
            unsigned key = __float_as_uint(f.w);
            int X = (int)(key & 511u) - 256;
            int Y = (int)((key >> 9) & 511u) - 256;
            int Z = (int)((key >> 18) & 511u) - 256;
            int cx0 = clampi(X, GW-1),  cx1 = clampi(X+1, GW-1);
            int cy0 = clampi(Y, GH-1),  cy1 = clampi(Y+1, GH-1);
            int cz0 = clampi(Z, GD-1),  cz1 = clampi(Z+1, GD-1);
            unsigned pk = (unsigned)cx0 | ((unsigned)cx1 << 8)
                        | ((unsigned)cy0 << 16) | ((unsigned)cy1 << 24);
            int st0 = ((unsigned)(cz0 - oz) < 8u) ? (cz0 - oz) : 255;
            int st1 = ((unsigned)(cz1 - oz) < 8u) ? (cz1 - oz) : 255;
            sA[tid] = make_float4(f.x, f.y, f.z, __uint_as_float(pk));
            sZ[tid] = st0 | (st1 << 8);

            // ---- gather (tile-local: corners within a 10^3 voxel window) ----
            int ray = (int)(p / (unsigned)NSAMP);
            int b   = gidx[ray];
            float feat[C_IN];
            {
                const float4* e4 = (const float4*)(enc + (size_t)ray * C_IN);
                #pragma unroll
                for (int q = 0; q < C_IN/4; ++q) {
                    float4 v = e4[q];
                    feat[4*q+0] = v.x; feat[4*q+1] = v.y;
                    feat[4*q+2] = v.z; feat[4*q+3] = v.w;
                }
            }
            int gxa[2] = { cx0, cx1 };
            int gya[2] = { cy0, cy1 };
            int gza[2] = { cz0, cz1 };
            float wxa[2] = { 1.0f - f.x, f.x };
            float wya[2] = { 1.0f - f.y, f.y };
            float wza[2] = { 1.0f - f.z, f.z };
            #pragma unroll
            for (int dz = 0; dz < 2; ++dz)
            #pragma unroll
            for (int dy = 0; dy < 2; ++dy)
            #pragma unroll
            for (int dx = 0; dx < 2; ++dx) {
                float wq = wza[dz] * wya[dy] * wxa[dx];
                size_t flat = ((((size_t)b * GD + gza[dz]) * GH + gya[dy]) * GW + gxa[dx]) * C_IN;
                const float4* g4 = (const float4*)(grid + flat);
                #pragma unroll
                for (int q = 0; q < C_IN/4; ++q) {
                    float4 v = g4[q];
                    feat[4*q+0] = fmaf(wq, v.x, feat[4*q+0]);
                    feat[4*q+1] = fmaf(wq, v.y, feat[4*q+1]);
                    feat[4*q+2] = fmaf(wq, v.z, feat[4*q+2]);
                    feat[4*q+3] = fmaf(wq, v.w, feat[4*q+3]);
                }
            }

            // ---- MLP (weights wave-uniform -> scalar loads) ----
            float h[C_HID];
            #pragma unroll
            for (int j = 0; j < C_HID; ++j) h[j] = b0[j];
            #pragma unroll
            for (int i = 0; i < C_IN; ++i) {
                float xi = feat[i];
                #pragma unroll
                for (int j = 0; j < C_HID; ++j) h[j] = fmaf(xi, W0[i*C_HID + j], h[j]);
            }
            #pragma unroll
            for (int j = 0; j < C_HID; ++j) h[j] = fmaxf(h[j], 0.0f);

            float o[C_OUT];
            #pragma unroll
            for (int j = 0; j < C_OUT; ++j) o[j] = b1[j];
            #pragma unroll
            for (int i = 0; i < C_HID; ++i) {
                float hi = h[i];
                #pragma unroll
                for (int j = 0; j < C_OUT; ++j) o[j] = fmaf(hi, W1[i*C_OUT + j], o[j]);
            }
            #pragma unroll
            for (int q = 0; q < 4; ++q)
                sO[q*CHUNK + tid] = make_float4(o[4*q+0], o[4*q+1], o[4*q+2], o[4*q+3]);
        } else {
            sZ[tid] = 255 | (255 << 8);   // sentinel: hits no wave
        }
        __syncthreads();

        const int4* sZ4 = (const int4*)sZ;
        int n4 = (n + 3) & ~3;
        for (int jb = 0; jb < n4; jb += 4) {
            int4 z4 = sZ4[jb >> 2];
            #pragma unroll
            for (int k = 0; k < 4; ++k) {
                int zz  = (k==0) ? z4.x : (k==1) ? z4.y : (k==2) ? z4.z : z4.w;
                int st0 = zz & 255, st1 = (zz >> 8) & 255;
                bool hitA = (st0 == l0) | (st1 == l0);   // wave-uniform
                bool hitB = (st0 == l1) | (st1 == l1);   // wave-uniform
                if (!(hitA | hitB)) continue;
                int j = jb + k;
                float4 a = sA[j];
                unsigned pk = __float_as_uint(a.w);
                int cx0 = (int)(pk & 255u),         cx1 = (int)((pk >> 8) & 255u);
                int cy0 = (int)((pk >> 16) & 255u), cy1 = (int)(pk >> 24);

                float wx = ((vxa == cx0) ? 1.0f - a.x : 0.0f)
                         + ((vxa == cx1) ? a.x        : 0.0f);
                float wy = ((vya == cy0) ? 1.0f - a.y : 0.0f)
                         + ((vya == cy1) ? a.y        : 0.0f);
                float wxy = wx * wy;

                if (hitA) {
                    float wzA = ((st0 == l0) ? 1.0f - a.z : 0.0f)
                              + ((st1 == l0) ? a.z        : 0.0f);
                    float wA = wxy * wzA;
                    #pragma unroll
                    for (int q = 0; q < 4; ++q) {
                        float4 ov = sO[q*CHUNK + j];
                        accA[4*q+0] = fmaf(wA, ov.x, accA[4*q+0]);
                        accA[4*q+1] = fmaf(wA, ov.y, accA[4*q+1]);
                        accA[4*q+2] = fmaf(wA, ov.z, accA[4*q+2]);
                        accA[4*q+3] = fmaf(wA, ov.w, accA[4*q+3]);
                    }
                }
                if (hitB) {
                    float wzB = ((st0 == l1) ? 1.0f - a.z : 0.0f)
                              + ((st1 == l1) ? a.z        : 0.0f);
                    float wB = wxy * wzB;
                    #pragma unroll
                    for (int q = 0; q < 4; ++q) {
                        float4 ov = sO[q*CHUNK + j];
                        accB[4*q+0] = fmaf(wB, ov.x, accB[4*q+0]);
                        accB[4*q+1] = fmaf(wB, ov.y, accB[4*q+1]);
                        accB[4*q+2] = fmaf(wB, ov.z, accB[4*q+2]);
                        accB[4*q+3] = fmaf(wB, ov.w, accB[4*q+3]);
                    }
                }
            }
        }
        __syncthreads();
    }

    // ---- dense register writeback (full coverage -> no memset needed) ----
    size_t baseA = ((((size_t)(oz + l0)) * GH + vya) * GW + vxa) * C_OUT;
    size_t baseB = ((((size_t)(oz + l1)) * GH + vya) * GW + vxa) * C_OUT;
    #pragma unroll
    for (int q = 0; q < 4; ++q) {
        *(float4*)(out + baseA + 4*q) = make_float4(accA[4*q+0], accA[4*q+1], accA[4*q+2], accA[4*q+3]);
        *(float4*)(out + baseB + 4*q) = make_float4(accB[4*q+0], accB[4*q+1], accB[4*q+2], accB[4*q+3]);
    }
}

// ============================================================================
// Fallback (round-3 fused kernel) if workspace is too small.
// ============================================================================
#define SEGS   8
#define SEGLEN (NSAMP / SEGS)
#define NTHREADS (N_RAYS * SEGS)

__global__ __launch_bounds__(256, 2) void splat_seg_kernel(
    const float* __restrict__ origins, const float* __restrict__ dirs,
    const float* __restrict__ nearv,   const float* __restrict__ farv,
    const float* __restrict__ enc,     const int*   __restrict__ gidx,
    const float* __restrict__ grid,    const float* __restrict__ W0,
    const float* __restrict__ b0,      const float* __restrict__ W1,
    const float* __restrict__ b1,      float* __restrict__ out)
{
    int tid = blockIdx.x * blockDim.x + threadIdx.x;
    if (tid >= NTHREADS) return;
    int ray = tid / SEGS;
    int seg = tid - ray * SEGS;
    float nr = nearv[ray], fr = farv[ray];
    float ox = origins[3*ray+0], oy = origins[3*ray+1], oz = origins[3*ray+2];
    float rdx = dirs[3*ray+0],   rdy = dirs[3*ray+1],   rdz = dirs[3*ray+2];
    int   b  = gidx[ray];
    float accv[8][C_OUT];
    #pragma unroll
    for (int sl = 0; sl < 8; ++sl)
        #pragma unroll
        for (int c = 0; c < C_OUT; ++c) accv[sl][c] = 0.0f;
    int Xp = 0, Yp = 0, Zp = 0;
    #pragma unroll 1
    for (int k = 0; k < SEGLEN; ++k) {
        int s = seg * SEGLEN + k;
        float t  = nr + (fr - nr) * ((float)s * (1.0f / (NSAMP - 1)));
        float px = fmaf(t, rdx, ox);
        float py = fmaf(t, rdy, oy);
        float pz = fmaf(t, rdz, oz);
        float cx = ((px + 1.0f) * (float)GW - 1.0f) * 0.5f;
        float cy = ((py + 1.0f) * (float)GH - 1.0f) * 0.5f;
        float cz = ((pz + 1.0f) * (float)GD - 1.0f) * 0.5f;
        float fxf = floorf(cx), fyf = floorf(cy), fzf = floorf(cz);
        float fx = cx - fxf, fy = cy - fyf, fz = cz - fzf;
        int X = (int)fxf, Y = (int)fyf, Z = (int)fzf;
        if (k == 0) { Xp = X; Yp = Y; Zp = Z; }
        else if (X != Xp || Y != Yp || Z != Zp) {
            bool fXm[2], fYm[2], fZm[2];
            int  vx[2], vy[2], vz[2];
            #pragma unroll
            for (int p = 0; p < 2; ++p) {
                int xo = Xp + ((Xp ^ p) & 1), xn = X + ((X ^ p) & 1);
                fXm[p] = (xo != xn);  vx[p] = clampi(xo, GW-1);
                int yo = Yp + ((Yp ^ p) & 1), yn = Y + ((Y ^ p) & 1);
                fYm[p] = (yo != yn);  vy[p] = clampi(yo, GH-1);
                int zo = Zp + ((Zp ^ p) & 1), zn = Z + ((Z ^ p) & 1);
                fZm[p] = (zo != zn);  vz[p] = clampi(zo, GD-1);
            }
            #pragma unroll
            for (int pxi = 0; pxi < 2; ++pxi)
            #pragma unroll
            for (int pyi = 0; pyi < 2; ++pyi)
            #pragma unroll
            for (int pzi = 0; pzi < 2; ++pzi) {
                const int sl = pxi*4 + pyi*2 + pzi;
                if (fXm[pxi] | fYm[pyi] | fZm[pzi]) {
                    size_t flat = ((((size_t)b * GD + vz[pzi]) * GH + vy[pyi]) * GW + vx[pxi]) * C_OUT;
                    float* op = out + flat;
                    #pragma unroll
                    for (int c = 0; c < C_OUT; ++c) { atomicAdd(op + c, accv[sl][c]); accv[sl][c] = 0.0f; }
                }
            }
            Xp = X; Yp = Y; Zp = Z;
        }
        float feat[C_IN];
        {
            const float4* e4 = (const float4*)(enc + (size_t)ray * C_IN);
            #pragma unroll
            for (int q = 0; q < C_IN/4; ++q) {
                float4 v = e4[q];
                feat[4*q+0] = v.x; feat[4*q+1] = v.y; feat[4*q+2] = v.z; feat[4*q+3] = v.w;
            }
        }
        int gx[2] = { clampi(X, GW-1), clampi(X+1, GW-1) };
        int gy[2] = { clampi(Y, GH-1), clampi(Y+1, GH-1) };
        int gz[2] = { clampi(Z, GD-1), clampi(Z+1, GD-1) };
        float wxa[2] = { 1.0f - fx, fx };
        float wya[2] = { 1.0f - fy, fy };
        float wza[2] = { 1.0f - fz, fz };
        #pragma unroll
        for (int dz = 0; dz < 2; ++dz)
        #pragma unroll
        for (int dy = 0; dy < 2; ++dy)
        #pragma unroll
        for (int dx = 0; dx < 2; ++dx) {
            float w = wza[dz] * wya[dy] * wxa[dx];
            size_t flat = ((((size_t)b * GD + gz[dz]) * GH + gy[dy]) * GW + gx[dx]) * C_IN;
            const float4* g4 = (const float4*)(grid + flat);
            #pragma unroll
            for (int q = 0; q < C_IN/4; ++q) {
                float4 v = g4[q];
                feat[4*q+0] = fmaf(w, v.x, feat[4*q+0]);
                feat[4*q+1] = fmaf(w, v.y, feat[4*q+1]);
                feat[4*q+2] = fmaf(w, v.z, feat[4*q+2]);
                feat[4*q+3] = fmaf(w, v.w, feat[4*q+3]);
            }
        }
        float h[C_HID];
        #pragma unroll
        for (int j = 0; j < C_HID; ++j) h[j] = b0[j];
        #pragma unroll
        for (int i = 0; i < C_IN; ++i) {
            float xi = feat[i];
            #pragma unroll
            for (int j = 0; j < C_HID; ++j) h[j] = fmaf(xi, W0[i*C_HID + j], h[j]);
        }
        #pragma unroll
        for (int j = 0; j < C_HID; ++j) h[j] = fmaxf(h[j], 0.0f);
        float o[C_OUT];
        #pragma unroll
        for (int j = 0; j < C_OUT; ++j) o[j] = b1[j];
        #pragma unroll
        for (int i = 0; i < C_HID; ++i) {
            float hi = h[i];
            #pragma unroll
            for (int j = 0; j < C_OUT; ++j) o[j] = fmaf(hi, W1[i*C_OUT + j], o[j]);
        }
        float wxs[2], wys[2], wzs[2];
        #pragma unroll
        for (int p = 0; p < 2; ++p) {
            wxs[p] = ((X & 1) == p) ? (1.0f - fx) : fx;
            wys[p] = ((Y & 1) == p) ? (1.0f - fy) : fy;
            wzs[p] = ((Z & 1) == p) ? (1.0f - fz) : fz;
        }
        #pragma unroll
        for (int pxi = 0; pxi < 2; ++pxi)
        #pragma unroll
        for (int pyi = 0; pyi < 2; ++pyi)
        #pragma unroll
        for (int pzi = 0; pzi < 2; ++pzi) {
            const int sl = pxi*4 + pyi*2 + pzi;
            float w = wxs[pxi] * wys[pyi] * wzs[pzi];
            #pragma unroll
            for (int c = 0; c < C_OUT; ++c) accv[sl][c] = fmaf(w, o[c], accv[sl][c]);
        }
    }
    #pragma unroll
    for (int pxi = 0; pxi < 2; ++pxi)
    #pragma unroll
    for (int pyi = 0; pyi < 2; ++pyi)
    #pragma unroll
    for (int pzi = 0; pzi < 2; ++pzi) {
        const int sl = pxi*4 + pyi*2 + pzi;
        int vx = clampi(Xp + ((Xp ^ pxi) & 1), GW-1);
        int vy = clampi(Yp + ((Yp ^ pyi) & 1), GH-1);
        int vz = clampi(Zp + ((Zp ^ pzi) & 1), GD-1);
        size_t flat = ((((size_t)b * GD + vz) * GH + vy) * GW + vx) * C_OUT;
        float* op = out + flat;
        #pragma unroll
        for (int c = 0; c < C_OUT; ++c) atomicAdd(op + c, accv[sl][c]);
    }
}

// ============================================================================
extern "C" void kernel_launch(void* const* d_in, const int* in_sizes, int n_in,
                              void* d_out, int out_size, void* d_ws, size_t ws_size,
                              hipStream_t stream) {
    const float* origins = (const float*)d_in[0];
    const float* dirs    = (const float*)d_in[1];
    const float* nearv   = (const float*)d_in[2];
    const float* farv    = (const float*)d_in[3];
    const float* enc     = (const float*)d_in[4];
    const int*   gidx    = (const int*)  d_in[5];
    const float* grid    = (const float*)d_in[6];
    const float* W0      = (const float*)d_in[7];
    const float* b0      = (const float*)d_in[8];
    const float* W1      = (const float*)d_in[9];
    const float* b1      = (const float*)d_in[10];
    float* out = (float*)d_out;

    const size_t PF_B = (size_t)M_PTS * 16;         // 25,165,824
    const size_t EN_B = (size_t)M_PTS * 8 * 4;      // 50,331,648 (hard bound)
    const size_t CT_B = (size_t)NTILES * 4;
    const size_t NEED = PF_B + EN_B + 4 * CT_B;

    if (ws_size < NEED) {
        // fallback: fused register-merged scatter (round-3 path)
        hipMemsetAsync(out, 0, (size_t)out_size * sizeof(float), stream);
        splat_seg_kernel<<<NTHREADS/256, 256, 0, stream>>>(
            origins, dirs, nearv, farv, enc, gidx, grid, W0, b0, W1, b1, out);
        return;
    }

    char* w = (char*)d_ws;
    float4*   pf      = (float4*)   w;              w += PF_B;
    unsigned* entries = (unsigned*) w;              w += EN_B;
    unsigned* counts  = (unsigned*) w;              w += CT_B;
    unsigned* offsets = (unsigned*) w;              w += CT_B;
    unsigned* alloc   = (unsigned*) w;              w += CT_B;
    unsigned* order   = (unsigned*) w;              w += CT_B;

    hipMemsetAsync(counts, 0, CT_B, stream);
    k1_pos<<<M_PTS/256, 256, 0, stream>>>(origins, dirs, nearv, farv, pf, counts);
    k2_scan<<<1, 256, 0, stream>>>(counts, offsets, alloc, order);
    k3_scatter<<<M_PTS/256, 256, 0, stream>>>(pf, alloc, entries);
    k4_fused<<<NTILES, 256, 0, stream>>>(pf, entries, offsets, alloc, order,
                                         enc, gidx, grid, W0, b0, W1, b1, out);
    // K4 writes every output voxel densely -> no output memset needed.
}